// Round 1
// baseline (348.780 us; speedup 1.0000x reference)
//
#include <hip/hip_runtime.h>
#include <hip/hip_bf16.h>

typedef __attribute__((ext_vector_type(8))) short bf16x8;
typedef __attribute__((ext_vector_type(4))) float f32x4;

#define AS1 __attribute__((address_space(1)))
#define AS3 __attribute__((address_space(3)))

__device__ __forceinline__ unsigned short f2bf(float f) {
  unsigned u = __float_as_uint(f);
  u += 0x7fff + ((u >> 16) & 1);   // RNE
  return (unsigned short)(u >> 16);
}

__device__ __forceinline__ void gload_lds16(const void* g, void* l) {
  __builtin_amdgcn_global_load_lds((const AS1 unsigned int*)g,
                                   (AS3 unsigned int*)l, 16, 0, 0);
}

// ---------------------------------------------------------------------------
// C[M,N] = scale * (A[M,K] @ Bt[N,K]^T) + bias.  A,Bt bf16 row-major,
// C fp32 or bf16(ushort). 128x128 tile, BK=32, 256 thr = 4 waves (2x2),
// each wave 4x4 of 16x16x32 MFMA. global_load_lds width-16 staging (m97).
// ---------------------------------------------------------------------------
template <typename OutT, bool BIAS>
__global__ void gemm_bt(const unsigned short* __restrict__ A,
                        const unsigned short* __restrict__ Bt,
                        OutT* __restrict__ C,
                        const float* __restrict__ bias,
                        int M, int N, int Kd,
                        int lda, int ldb, int ldc,
                        long sA, long sB, long sC,
                        float scale) {
  __shared__ unsigned short ldsA[128 * 32];
  __shared__ unsigned short ldsB[128 * 32];
  const int bz = blockIdx.z;
  A  += (size_t)bz * sA + (size_t)blockIdx.x * 128 * lda;
  Bt += (size_t)bz * sB + (size_t)blockIdx.y * 128 * ldb;

  const int tid  = threadIdx.x;
  const int wave = tid >> 6;
  const int lane = tid & 63;
  const int wm   = (wave >> 1) * 64;   // wave row offset within 128-tile
  const int wn   = (wave & 1) * 64;    // wave col offset
  const int quad = lane >> 4;
  const int l16  = lane & 15;
  const int srow = wave * 16 + (lane >> 2);  // staging row (0..63)
  const int scol = (lane & 3) * 8;           // staging col (bf16 elems)

  f32x4 acc[4][4] = {};

  for (int k0 = 0; k0 < Kd; k0 += 32) {
    __syncthreads();
    gload_lds16(A  + (size_t)srow * lda + k0 + scol,        (char*)ldsA + wave * 1024);
    gload_lds16(A  + (size_t)(srow + 64) * lda + k0 + scol, (char*)ldsA + 4096 + wave * 1024);
    gload_lds16(Bt + (size_t)srow * ldb + k0 + scol,        (char*)ldsB + wave * 1024);
    gload_lds16(Bt + (size_t)(srow + 64) * ldb + k0 + scol, (char*)ldsB + 4096 + wave * 1024);
    __syncthreads();

    bf16x8 af[4], bfr[4];
#pragma unroll
    for (int i = 0; i < 4; ++i)
      af[i] = *(const bf16x8*)&ldsA[(wm + i * 16 + l16) * 32 + quad * 8];
#pragma unroll
    for (int j = 0; j < 4; ++j)
      bfr[j] = *(const bf16x8*)&ldsB[(wn + j * 16 + l16) * 32 + quad * 8];
#pragma unroll
    for (int i = 0; i < 4; ++i)
#pragma unroll
      for (int j = 0; j < 4; ++j)
        acc[i][j] = __builtin_amdgcn_mfma_f32_16x16x32_bf16(af[i], bfr[j], acc[i][j], 0, 0, 0);
  }

  const int row0 = blockIdx.x * 128 + wm;
  const int col0 = blockIdx.y * 128 + wn;
  C += (size_t)bz * sC;
#pragma unroll
  for (int i = 0; i < 4; ++i) {
#pragma unroll
    for (int j = 0; j < 4; ++j) {
      const int col = col0 + j * 16 + l16;
      const float bv = BIAS ? bias[col] : 0.0f;
#pragma unroll
      for (int r = 0; r < 4; ++r) {
        const int row = row0 + i * 16 + quad * 4 + r;
        const float v = acc[i][j][r] * scale + bv;
        if constexpr (sizeof(OutT) == 4)
          C[(size_t)row * ldc + col] = v;
        else
          C[(size_t)row * ldc + col] = (OutT)f2bf(v);
      }
    }
  }
}

// fp32 -> bf16 flat convert (4 elems/thread)
__global__ void cvt_x(const float* __restrict__ in, unsigned short* __restrict__ out, int n4) {
  const int i = blockIdx.x * blockDim.x + threadIdx.x;
  if (i < n4) {
    const float4 v = ((const float4*)in)[i];
    uint2 o;
    o.x = (unsigned)f2bf(v.x) | ((unsigned)f2bf(v.y) << 16);
    o.y = (unsigned)f2bf(v.z) | ((unsigned)f2bf(v.w) << 16);
    ((uint2*)out)[i] = o;
  }
}

// fp32 [rows][cols] -> bf16 transposed [cols][rows]. block (64,4), 64x64 tiles.
__global__ void cvtT_w(const float* __restrict__ in, unsigned short* __restrict__ out,
                       int rows, int cols) {
  __shared__ unsigned short tile[64][65];
  const int r0 = blockIdx.y * 64, c0 = blockIdx.x * 64;
  for (int i = threadIdx.y; i < 64; i += 4)
    tile[i][threadIdx.x] = f2bf(in[(size_t)(r0 + i) * cols + c0 + threadIdx.x]);
  __syncthreads();
  for (int i = threadIdx.y; i < 64; i += 4)
    out[(size_t)(c0 + i) * rows + r0 + threadIdx.x] = tile[threadIdx.x][i];
}

// bf16 [b][rows][cols] -> [b][cols][rows]
__global__ void transpose_bf16(const unsigned short* __restrict__ in,
                               unsigned short* __restrict__ out, int rows, int cols) {
  __shared__ unsigned short tile[64][65];
  const int b = blockIdx.z;
  in  += (size_t)b * rows * cols;
  out += (size_t)b * rows * cols;
  const int r0 = blockIdx.y * 64, c0 = blockIdx.x * 64;
  for (int i = threadIdx.y; i < 64; i += 4)
    tile[i][threadIdx.x] = in[(size_t)(r0 + i) * cols + c0 + threadIdx.x];
  __syncthreads();
  for (int i = threadIdx.y; i < 64; i += 4)
    out[(size_t)(c0 + i) * rows + r0 + threadIdx.x] = tile[threadIdx.x][i];
}

// One block per row of 2048 fp32 scores. Full row in registers (8/thread).
// Softmax in fp32, result written IN PLACE as bf16 (row stride 4096 elems).
__global__ __launch_bounds__(256) void softmax_inplace(float* __restrict__ scores) {
  float* p = scores + (size_t)blockIdx.x * 2048;
  const int t = threadIdx.x;
  float4 v0 = ((const float4*)p)[t * 2];
  float4 v1 = ((const float4*)p)[t * 2 + 1];

  float m = fmaxf(fmaxf(fmaxf(v0.x, v0.y), fmaxf(v0.z, v0.w)),
                  fmaxf(fmaxf(v1.x, v1.y), fmaxf(v1.z, v1.w)));
#pragma unroll
  for (int off = 32; off; off >>= 1) m = fmaxf(m, __shfl_xor(m, off, 64));

  __shared__ float red[4];
  __shared__ float bcast[2];
  const int wave = t >> 6, lane = t & 63;
  if (lane == 0) red[wave] = m;
  __syncthreads();
  if (t == 0) bcast[0] = fmaxf(fmaxf(red[0], red[1]), fmaxf(red[2], red[3]));
  __syncthreads();
  m = bcast[0];

  v0.x = __expf(v0.x - m); v0.y = __expf(v0.y - m);
  v0.z = __expf(v0.z - m); v0.w = __expf(v0.w - m);
  v1.x = __expf(v1.x - m); v1.y = __expf(v1.y - m);
  v1.z = __expf(v1.z - m); v1.w = __expf(v1.w - m);

  float s = v0.x + v0.y + v0.z + v0.w + v1.x + v1.y + v1.z + v1.w;
#pragma unroll
  for (int off = 32; off; off >>= 1) s += __shfl_xor(s, off, 64);
  if (lane == 0) red[wave] = s;
  __syncthreads();
  if (t == 0) bcast[1] = red[0] + red[1] + red[2] + red[3];
  __syncthreads();
  const float inv = 1.0f / bcast[1];

  uint4 ov;
  ov.x = (unsigned)f2bf(v0.x * inv) | ((unsigned)f2bf(v0.y * inv) << 16);
  ov.y = (unsigned)f2bf(v0.z * inv) | ((unsigned)f2bf(v0.w * inv) << 16);
  ov.z = (unsigned)f2bf(v1.x * inv) | ((unsigned)f2bf(v1.y * inv) << 16);
  ov.w = (unsigned)f2bf(v1.z * inv) | ((unsigned)f2bf(v1.w * inv) << 16);
  ((uint4*)p)[t] = ov;   // bytes [t*16, t*16+16) of this row's slot
}

// ---------------------------------------------------------------------------
extern "C" void kernel_launch(void* const* d_in, const int* in_sizes, int n_in,
                              void* d_out, int out_size, void* d_ws, size_t ws_size,
                              hipStream_t stream) {
  const float* x  = (const float*)d_in[0];
  const float* Wq = (const float*)d_in[1];
  const float* bq = (const float*)d_in[2];
  const float* Wk = (const float*)d_in[3];
  const float* bk = (const float*)d_in[4];
  const float* Wv = (const float*)d_in[5];
  const float* bv = (const float*)d_in[6];
  const float* Wo = (const float*)d_in[7];
  const float* bo = (const float*)d_in[8];
  float* out = (float*)d_out;

  char* ws = (char*)d_ws;
  const size_t XB = 8192UL * 1024 * 2;   // 16 MiB bf16 [8192,1024]
  const size_t WB = 1024UL * 1024 * 2;   // 2 MiB bf16 [1024,1024]
  unsigned short* xb   = (unsigned short*)(ws);
  unsigned short* Wqb  = (unsigned short*)(ws + XB);
  unsigned short* Wkb  = (unsigned short*)(ws + XB + WB);
  unsigned short* Wvb  = (unsigned short*)(ws + XB + 2 * WB);
  unsigned short* Wob  = (unsigned short*)(ws + XB + 3 * WB);
  unsigned short* Qb   = (unsigned short*)(ws + XB + 4 * WB);
  unsigned short* Kb   = (unsigned short*)(ws + 2 * XB + 4 * WB);
  unsigned short* Vb   = (unsigned short*)(ws + 3 * XB + 4 * WB);
  unsigned short* Vtb  = (unsigned short*)(ws + 4 * XB + 4 * WB);
  unsigned short* ctxb = (unsigned short*)(ws + 5 * XB + 4 * WB);
  float*          sc   = (float*)(ws + 6 * XB + 4 * WB);  // 64 MiB fp32 [4,2048,2048]

  const dim3 blk(256);

  // converts
  cvt_x<<<2097152 / 256, 256, 0, stream>>>(x, xb, 2097152);
  cvtT_w<<<dim3(16, 16), dim3(64, 4), 0, stream>>>(Wq, Wqb, 1024, 1024);
  cvtT_w<<<dim3(16, 16), dim3(64, 4), 0, stream>>>(Wk, Wkb, 1024, 1024);
  cvtT_w<<<dim3(16, 16), dim3(64, 4), 0, stream>>>(Wv, Wvb, 1024, 1024);
  cvtT_w<<<dim3(16, 16), dim3(64, 4), 0, stream>>>(Wo, Wob, 1024, 1024);

  // Q,K,V projections: [8192,1024] = xb @ W^T-layout + bias
  gemm_bt<unsigned short, true><<<dim3(64, 8, 1), blk, 0, stream>>>(
      xb, Wqb, Qb, bq, 8192, 1024, 1024, 1024, 1024, 1024, 0, 0, 0, 1.0f);
  gemm_bt<unsigned short, true><<<dim3(64, 8, 1), blk, 0, stream>>>(
      xb, Wkb, Kb, bk, 8192, 1024, 1024, 1024, 1024, 1024, 0, 0, 0, 1.0f);
  gemm_bt<unsigned short, true><<<dim3(64, 8, 1), blk, 0, stream>>>(
      xb, Wvb, Vb, bv, 8192, 1024, 1024, 1024, 1024, 1024, 0, 0, 0, 1.0f);

  // V^T per batch: [4][1024][2048]
  transpose_bf16<<<dim3(16, 32, 4), dim3(64, 4), 0, stream>>>(Vb, Vtb, 2048, 1024);

  // scores = (Q @ K^T) / 32, fp32, per batch
  gemm_bt<float, false><<<dim3(16, 16, 4), blk, 0, stream>>>(
      Qb, Kb, sc, nullptr, 2048, 2048, 1024, 1024, 1024, 2048,
      2048L * 1024, 2048L * 1024, 2048L * 2048, 0.03125f);

  // softmax rows (in-place fp32 -> bf16, row stride 4096 bf16)
  softmax_inplace<<<8192, 256, 0, stream>>>(sc);

  // ctx = attn @ V  (attn bf16 lda=4096, Vt is B^T layout)
  gemm_bt<unsigned short, false><<<dim3(16, 8, 4), blk, 0, stream>>>(
      (unsigned short*)sc, Vtb, ctxb, nullptr, 2048, 1024, 2048, 4096, 2048, 1024,
      2048L * 4096, 1024L * 2048, 2048L * 1024, 1.0f);

  // out = ctx @ Wo + bo (fp32 out)
  gemm_bt<float, true><<<dim3(64, 8, 1), blk, 0, stream>>>(
      ctxb, Wob, out, bo, 8192, 1024, 1024, 1024, 1024, 1024, 0, 0, 0, 1.0f);
}